// Round 1
// 575.599 us; speedup vs baseline: 1.1683x; 1.1683x over previous
//
#include <hip/hip_runtime.h>
#include <stdint.h>
#include <stddef.h>

// ---------------- problem constants ----------------
#define N_NODES  4096
#define N_EDGES  12288
#define EA_EDGES 16384      // N_EDGES + N_NODES self loops
#define NBATCH   64
#define CLIPD    768
#define HIDD     1024
#define C2D      3072
#define NEG_SLOPE 0.2f
#define MAXDEG   96         // in-degree ~Poisson(3); P(>96) ~ 0

typedef unsigned short u16;
typedef short bf16x8 __attribute__((ext_vector_type(8)));   // 8 bf16 = 4 VGPRs (guide §3)
typedef float f32x4  __attribute__((ext_vector_type(4)));

static __device__ __forceinline__ float b2f(u16 u) {
    union { float f; unsigned int i; } v; v.i = ((unsigned int)u) << 16; return v.f;
}
static __device__ __forceinline__ u16 f2b(float f) {
    union { float f; unsigned int i; } v; v.f = f;
    unsigned int r = (v.i + 0x7fffu + ((v.i >> 16) & 1u)) >> 16;   // RNE
    return (u16)r;
}
// dtype-polymorphic 4-element vector load (fp32 or bf16 source) -> 4 floats
static __device__ __forceinline__ void ld4(const float* p, float v[4]) {
    float4 t = *(const float4*)p;
    v[0] = t.x; v[1] = t.y; v[2] = t.z; v[3] = t.w;
}
static __device__ __forceinline__ void ld4(const u16* p, float v[4]) {
    ushort4 t = *(const ushort4*)p;
    v[0] = b2f(t.x); v[1] = b2f(t.y); v[2] = b2f(t.z); v[3] = b2f(t.w);
}

static __device__ __forceinline__ float wsum(float v) {
#pragma unroll
    for (int o = 32; o > 0; o >>= 1) v += __shfl_xor(v, o, 64);
    return v;
}
static __device__ __forceinline__ float wmax(float v) {
#pragma unroll
    for (int o = 32; o > 0; o >>= 1) v = fmaxf(v, __shfl_xor(v, o, 64));
    return v;
}
static __device__ __forceinline__ int lower_bound(const int* a, int n, int key) {
    int lo = 0, hi = n;
    while (lo < hi) { int m = (lo + hi) >> 1; if (a[m] < key) lo = m + 1; else hi = m; }
    return lo;
}

// async global->LDS, 16B per lane. LDS dst is wave-uniform base + lane*16 (m104/m108);
// our LDS offsets are exactly tid*16, satisfying that constraint.
#define GLD16(gp, lp)                                                            \
    __builtin_amdgcn_global_load_lds((const __attribute__((address_space(1))) void*)(gp), \
                                     (__attribute__((address_space(3))) void*)(lp), 16, 0, 0)

// ---------------- CSR build ----------------
__global__ void k_deg(const int* __restrict__ dst, int* __restrict__ deg) {
    int e = blockIdx.x * 256 + threadIdx.x;
    if (e < N_EDGES) atomicAdd(&deg[dst[e]], 1);
}

__global__ void k_scan(const int* __restrict__ deg, int* __restrict__ offs) {
    __shared__ int s[1024];
    int t = threadIdx.x;
    int v[4]; int sum = 0;
#pragma unroll
    for (int i = 0; i < 4; i++) { v[i] = deg[t * 4 + i] + 1; sum += v[i]; }
    s[t] = sum; __syncthreads();
    for (int st = 1; st < 1024; st <<= 1) {
        int x = 0;
        if (t >= st) x = s[t - st];
        __syncthreads();
        s[t] += x;
        __syncthreads();
    }
    int run = s[t] - sum;
#pragma unroll
    for (int i = 0; i < 4; i++) { offs[t * 4 + i] = run; run += v[i]; }
    if (t == 1023) offs[N_NODES] = run;
}

__global__ void k_fill(const int* __restrict__ dst, const int* __restrict__ offs,
                       int* __restrict__ cur, int* __restrict__ csr) {
    int id = blockIdx.x * 256 + threadIdx.x;
    if (id >= EA_EDGES) return;
    int d = (id < N_EDGES) ? dst[id] : (id - N_EDGES);
    int p = atomicAdd(&cur[d], 1);
    csr[offs[d] + p] = id;
}

// ---------------- weight-side attention reductions (fp32 in, fp32 out) ----------------
// float4 over c (G13): 16B/lane loads on W and att rows.
__global__ void k_reduce_w(const float* __restrict__ W, const float* __restrict__ attA,
                           const float* __restrict__ attB, float* __restrict__ out,
                           int C, int col0) {
    int d = blockIdx.x, t = threadIdx.x;
    float acc[8] = {0, 0, 0, 0, 0, 0, 0, 0};
    for (int c = t * 4; c < C; c += 1024) {
#pragma unroll
        for (int h = 0; h < 4; h++) {
            float4 w = *(const float4*)&W[((size_t)d * 4 + h) * C + c];
            float4 a = *(const float4*)&attA[h * C + c];
            acc[h] += w.x * a.x + w.y * a.y + w.z * a.z + w.w * a.w;
            if (attB) {
                float4 bv = *(const float4*)&attB[h * C + c];
                acc[4 + h] += w.x * bv.x + w.y * bv.y + w.z * bv.z + w.w * bv.w;
            }
        }
    }
    __shared__ float red[4][8];
    int lane = t & 63, wv = t >> 6;
#pragma unroll
    for (int j = 0; j < 8; j++) acc[j] = wsum(acc[j]);
    if (lane == 0) {
#pragma unroll
        for (int j = 0; j < 8; j++) red[wv][j] = acc[j];
    }
    __syncthreads();
    if (t < 8) {
        float s = red[0][t] + red[1][t] + red[2][t] + red[3][t];
        if (attB) out[d * 8 + col0 + t] = s;
        else if (t < 4) out[d * 8 + col0 + t] = s;
    }
}

// skinny GEMV: out[row][0..7] = X[row,:] @ Wr[:,0..7]   (one wave per row, 4-wide k)
template <typename T>
__global__ void k_gemv8(const T* __restrict__ X, int K, const float* __restrict__ Wr,
                        float* __restrict__ out, int rows) {
    int wv = threadIdx.x >> 6, lane = threadIdx.x & 63;
    int row = blockIdx.x * 4 + wv;
    if (row >= rows) return;
    float acc[8] = {0, 0, 0, 0, 0, 0, 0, 0};
    const T* xp = X + (size_t)row * K;
    for (int k = lane * 4; k < K; k += 256) {
        float xv[4]; ld4(xp + k, xv);
#pragma unroll
        for (int kk = 0; kk < 4; kk++) {
            const float4* w = (const float4*)(Wr + (size_t)(k + kk) * 8);
            float4 w0 = w[0], w1 = w[1];
            acc[0] += xv[kk] * w0.x; acc[1] += xv[kk] * w0.y;
            acc[2] += xv[kk] * w0.z; acc[3] += xv[kk] * w0.w;
            acc[4] += xv[kk] * w1.x; acc[5] += xv[kk] * w1.y;
            acc[6] += xv[kk] * w1.z; acc[7] += xv[kk] * w1.w;
        }
    }
#pragma unroll
    for (int j = 0; j < 8; j++) acc[j] = wsum(acc[j]);
    if (lane == 0) {
#pragma unroll
        for (int j = 0; j < 8; j++) out[(size_t)row * 8 + j] = acc[j];
    }
}

// self-loop edge attention = mean of incident real edges' a_e (linearity of mean_attr @ w)
__global__ void k_selfloop(float* __restrict__ ae, const int* __restrict__ csr,
                           const int* __restrict__ offs, const int* __restrict__ deg) {
    int n = blockIdx.x * 256 + threadIdx.x;
    if (n >= N_NODES) return;
    float s[8] = {0, 0, 0, 0, 0, 0, 0, 0};
    int lo = offs[n], hi = offs[n + 1];
    for (int i = lo; i < hi; i++) {
        int eid = csr[i];
        if (eid < N_EDGES) {
            const float4* p = (const float4*)(ae + (size_t)eid * 8);
            float4 a = p[0], b = p[1];
            s[0] += a.x; s[1] += a.y; s[2] += a.z; s[3] += a.w;
            s[4] += b.x; s[5] += b.y; s[6] += b.z; s[7] += b.w;
        }
    }
    float inv = 1.0f / (float)(deg[n] > 0 ? deg[n] : 1);
    float4* o = (float4*)(ae + (size_t)(N_EDGES + n) * 8);
    float4 o0, o1;
    o0.x = s[0] * inv; o0.y = s[1] * inv; o0.z = s[2] * inv; o0.w = s[3] * inv;
    o1.x = s[4] * inv; o1.y = s[5] * inv; o1.z = s[6] * inv; o1.w = s[7] * inv;
    o[0] = o0; o[1] = o1;
}

// per-dst-node attention softmax + aggregation in INPUT feature space:
// agg[n, d*4+h] = sum_e coef[e,h] * feat[src_e, d]  (bf16 out; column order = W's natural layout)
// R1: wave-parallel softmax (one wave per head, shuffle reduce) + 4-features/thread
// vector path (float4 / ushort4 loads, 4x ushort4 stores).
template <typename T>
__global__ void k_attn_agg(const T* __restrict__ feat, int D,
                           const float* __restrict__ asd, const float* __restrict__ ae, int aecol,
                           const int* __restrict__ offs, const int* __restrict__ csr,
                           const int* __restrict__ src, u16* __restrict__ agg) {
    int n = blockIdx.x, t = threadIdx.x;
    __shared__ int sl[MAXDEG];
    __shared__ float cf[MAXDEG][4];
    int lo = offs[n];
    int cnt = offs[n + 1] - lo;
    if (cnt > MAXDEG) cnt = MAXDEG;
    for (int i = t; i < cnt; i += 256) {
        int eid = csr[lo + i];
        int s = (eid < N_EDGES) ? src[eid] : n;
        sl[i] = s;
#pragma unroll
        for (int h = 0; h < 4; h++) {
            float al = asd[(size_t)s * 8 + h] + asd[(size_t)n * 8 + 4 + h] +
                       ae[(size_t)eid * 8 + aecol + h];
            cf[i][h] = (al >= 0.f) ? al : NEG_SLOPE * al;
        }
    }
    __syncthreads();
    {   // head = wave index: all 4 waves active, shuffle-reduce softmax (was 4-thread serial)
        int wv = t >> 6, lane = t & 63;
        float mx = -1e30f;
        for (int i = lane; i < cnt; i += 64) mx = fmaxf(mx, cf[i][wv]);
        mx = wmax(mx);
        float ds = 0.f;
        for (int i = lane; i < cnt; i += 64) {
            float e = __expf(cf[i][wv] - mx); cf[i][wv] = e; ds += e;
        }
        ds = wsum(ds);
        float inv = 1.0f / (ds + 1e-16f);
        for (int i = lane; i < cnt; i += 64) cf[i][wv] *= inv;
    }
    __syncthreads();
    for (int d4 = t * 4; d4 < D; d4 += 1024) {
        float a[4][4] = {};                     // [dj][head]
        for (int i = 0; i < cnt; i++) {
            float4 c4 = *(const float4*)cf[i];  // 4 heads, LDS broadcast
            float v[4]; ld4(feat + (size_t)sl[i] * D + d4, v);
#pragma unroll
            for (int dj = 0; dj < 4; dj++) {
                a[dj][0] += c4.x * v[dj]; a[dj][1] += c4.y * v[dj];
                a[dj][2] += c4.z * v[dj]; a[dj][3] += c4.w * v[dj];
            }
        }
        u16* op = agg + (size_t)n * 4 * D + (size_t)d4 * 4;
#pragma unroll
        for (int dj = 0; dj < 4; dj++) {
            ushort4 pk;
            pk.x = f2b(a[dj][0]); pk.y = f2b(a[dj][1]);
            pk.z = f2b(a[dj][2]); pk.w = f2b(a[dj][3]);
            *(ushort4*)(op + dj * 4) = pk;
        }
    }
}

// ---------------- transpose + downcast (fp32 [R,C] -> bf16 [C,R]) ----------------
// R1: ushort4 stores (was scalar u16, 2B/lane). LDS read pattern tile[s4+k][j]:
// bank = (4*(s4+k)+j)%32 covers all residues 2x per wave = conflict-free (m136).
__global__ void k_transpose(const float* __restrict__ in, u16* __restrict__ out, int R, int C) {
    __shared__ float tile[64][65];
    int tx = threadIdx.x, ty = threadIdx.y;
    int rb = blockIdx.y * 64, cb = blockIdx.x * 64;
    for (int i = ty; i < 64; i += 4) tile[i][tx] = in[(size_t)(rb + i) * C + cb + tx];
    __syncthreads();
    int linear = ty * 64 + tx;
#pragma unroll
    for (int jj = 0; jj < 4; jj++) {
        int idx = linear + jj * 256;
        int j = idx >> 4, s4 = (idx & 15) * 4;
        ushort4 pk;
        pk.x = f2b(tile[s4 + 0][j]);
        pk.y = f2b(tile[s4 + 1][j]);
        pk.z = f2b(tile[s4 + 2][j]);
        pk.w = f2b(tile[s4 + 3][j]);
        *(ushort4*)(out + (size_t)(cb + j) * R + rb + s4) = pk;
    }
}

// ---------------- MFMA GEMM: C = prelu(scale * A@Bt^T + bias) ----------------
// A [M,K] bf16 row-major, Bt [N,K] bf16 row-major. 128xBN tile, BK=64, 4 waves.
// BK=64 (R7->R8): halves barrier count per kernel (the m97-structure stall is the
// vmcnt(0)+s_barrier drain; m132's BK=128 regression was an occupancy cliff at
// 64KB LDS -- at 32KB/24KB we keep 5-6 blocks/CU >= the grid-imposed 3/2, so
// occupancy is unchanged while MFMA-per-barrier doubles).
// Chunk mapping: c -> row = c>>3, kb = (c&7) ^ (row&7).
//  * staging: lane-quads are 4-aligned in c, same row, kb = {0..3}^m or {4..7}^m
//    = one contiguous 64B half-line (XOR permutes within / flips halves) -- keeps
//    the R5 quarter-wave coalescing (the coalescer merges per 16-lane group).
//  * fragment read: lane (rl,q), k-half s reads chunk row*8 + ((q+4s)^(rl&7));
//    bank-quad = (q+4s)^(rl&7) covers all 8 quads, 2 lanes each = free (m136).
template <int BN>
__global__ __launch_bounds__(256, 2) void k_gemm(
        const u16* __restrict__ A, const u16* __restrict__ Bt, void* __restrict__ Cout,
        const float* __restrict__ bias, const float* __restrict__ prelu, float scale,
        int N, int K, int f32out) {
    constexpr int NJ = BN / 32;              // 16-wide n-subtiles per wave (2 waves along N)
    constexpr int NBCH = BN * 8 / 256;       // B chunks per thread (4 or 2)
    __shared__ __align__(16) u16 As[128 * 64];   // 16 KB
    __shared__ __align__(16) u16 Bs[BN * 64];    // 16 KB (BN=128) / 8 KB (BN=64)
    int tid = threadIdx.x;
    int lane = tid & 63, wv = tid >> 6;
    int m0 = blockIdx.y * 128, n0 = blockIdx.x * BN;
    const u16* agp[4]; u16* alp[4];
#pragma unroll
    for (int u = 0; u < 4; u++) {
        int c = tid + u * 256;
        int r = c >> 3, kb = (c & 7) ^ (r & 7);
        agp[u] = A + (size_t)(m0 + r) * K + kb * 8;
        alp[u] = As + c * 8;
    }
    const u16* bgp[NBCH]; u16* blp[NBCH];
#pragma unroll
    for (int u = 0; u < NBCH; u++) {
        int c = tid + u * 256;
        int r = c >> 3, kb = (c & 7) ^ (r & 7);
        bgp[u] = Bt + (size_t)(n0 + r) * K + kb * 8;
        blp[u] = Bs + c * 8;
    }
    int wm = wv & 1, wn = wv >> 1;
    int rl = lane & 15, q = lane >> 4;
    int swz = rl & 7;
    int mb = wm * 64 + rl;
    int nb = wn * (NJ * 16) + rl;
    f32x4 acc[4][NJ] = {};
    for (int k0 = 0; k0 < K; k0 += 64) {
        __syncthreads();                       // previous tile's LDS reads done
#pragma unroll
        for (int u = 0; u < 4; u++) { GLD16(agp[u], alp[u]); agp[u] += 64; }
#pragma unroll
        for (int u = 0; u < NBCH; u++) { GLD16(bgp[u], blp[u]); bgp[u] += 64; }
        __syncthreads();                       // drains vmcnt(0): staging landed
        bf16x8 af[4][2], bfr[NJ][2];
#pragma unroll
        for (int i = 0; i < 4; i++)
#pragma unroll
            for (int s = 0; s < 2; s++)
                af[i][s] = *(const bf16x8*)(As + (((mb + i * 16) * 8 + ((q + 4 * s) ^ swz)) * 8));
#pragma unroll
        for (int j = 0; j < NJ; j++)
#pragma unroll
            for (int s = 0; s < 2; s++)
                bfr[j][s] = *(const bf16x8*)(Bs + (((nb + j * 16) * 8 + ((q + 4 * s) ^ swz)) * 8));
#pragma unroll
        for (int i = 0; i < 4; i++)
#pragma unroll
            for (int j = 0; j < NJ; j++) {
                acc[i][j] = __builtin_amdgcn_mfma_f32_16x16x32_bf16(af[i][0], bfr[j][0], acc[i][j], 0, 0, 0);
                acc[i][j] = __builtin_amdgcn_mfma_f32_16x16x32_bf16(af[i][1], bfr[j][1], acc[i][j], 0, 0, 0);
            }
    }
    float pa = prelu[0];
    int r0w = (lane >> 4) * 4;
    int cc = lane & 15;
#pragma unroll
    for (int j = 0; j < NJ; j++) {
        int col = n0 + wn * (NJ * 16) + j * 16 + cc;
        float bv = bias[col];
#pragma unroll
        for (int i = 0; i < 4; i++) {
#pragma unroll
            for (int r = 0; r < 4; r++) {
                int row = m0 + wm * 64 + i * 16 + r0w + r;
                float v = acc[i][j][r] * scale + bv;
                v = (v >= 0.f) ? v : pa * v;
                if (f32out) ((float*)Cout)[(size_t)row * N + col] = v;
                else        ((u16*)Cout)[(size_t)row * N + col] = f2b(v);
            }
        }
    }
}

// ---------------- gate + pooling ----------------
__global__ void k_gate(const float* __restrict__ g2, const float* __restrict__ gW3,
                       const float* __restrict__ gb3, float* __restrict__ gate) {
    int wv = threadIdx.x >> 6, lane = threadIdx.x & 63;
    int n = blockIdx.x * 4 + wv;
    if (n >= N_NODES) return;
    float s = 0.f;
    const float* gp = g2 + (size_t)n * HIDD;
    for (int k = lane * 4; k < HIDD; k += 256) {
        float4 a = *(const float4*)(gp + k);
        float4 w = *(const float4*)(gW3 + k);
        s += a.x * w.x + a.y * w.y + a.z * w.z + a.w * w.w;
    }
    s = wsum(s);
    if (lane == 0) gate[n] = s + gb3[0];
}

// R1: split C2D across grid.y (64 -> 192 blocks; was 25% CU occupancy) and
// vectorize: ushort4 h2 loads (8B/lane), float4 stores. Softmax weights are
// recomputed per column-block (cheap: cnt<=256 gate reads).
__global__ void k_pool(const float* __restrict__ gate, const u16* __restrict__ h2,
                       const int* __restrict__ batch, float* __restrict__ out) {
    int b = blockIdx.x, t = threadIdx.x;
    int c = blockIdx.y * 1024 + t * 4;
    int lo = lower_bound(batch, N_NODES, b);
    int hi = lower_bound(batch, N_NODES, b + 1);
    int cnt = hi - lo;
    if (cnt <= 0) {
        float4 z; z.x = z.y = z.z = z.w = 0.f;
        *(float4*)(out + (size_t)b * C2D + c) = z;
        return;
    }
    if (cnt > 256) cnt = 256;   // multinomial(4096,1/64) max ~110; safety clamp
    __shared__ float w[256];
    __shared__ float red[4];
    int lane = t & 63, wv = t >> 6;
    float mx = -1e30f;
    for (int i = t; i < cnt; i += 256) mx = fmaxf(mx, gate[lo + i]);
    mx = wmax(mx);
    if (lane == 0) red[wv] = mx;
    __syncthreads();
    mx = fmaxf(fmaxf(red[0], red[1]), fmaxf(red[2], red[3]));
    __syncthreads();
    float ds = 0.f;
    for (int i = t; i < cnt; i += 256) { float e = __expf(gate[lo + i] - mx); w[i] = e; ds += e; }
    ds = wsum(ds);
    if (lane == 0) red[wv] = ds;
    __syncthreads();
    float inv = 1.0f / (red[0] + red[1] + red[2] + red[3] + 1e-16f);
    float4 acc; acc.x = acc.y = acc.z = acc.w = 0.f;
    const u16* hp = h2 + (size_t)lo * C2D + c;
    for (int i = 0; i < cnt; i++) {
        ushort4 hv = *(const ushort4*)hp; hp += C2D;
        float wi = w[i];
        acc.x += wi * b2f(hv.x); acc.y += wi * b2f(hv.y);
        acc.z += wi * b2f(hv.z); acc.w += wi * b2f(hv.w);
    }
    acc.x *= inv; acc.y *= inv; acc.z *= inv; acc.w *= inv;
    *(float4*)(out + (size_t)b * C2D + c) = acc;
}

// ---------------- launch ----------------
extern "C" void kernel_launch(void* const* d_in, const int* in_sizes, int n_in,
                              void* d_out, int out_size, void* d_ws, size_t ws_size,
                              hipStream_t stream) {
    (void)in_sizes; (void)n_in; (void)out_size; (void)ws_size;
    const float* x      = (const float*)d_in[0];
    const int*   eidx   = (const int*)d_in[1];
    const float* eattr  = (const float*)d_in[2];
    const int*   batch  = (const int*)d_in[3];
    const float* W1     = (const float*)d_in[4];
    const float* att_s1 = (const float*)d_in[5];
    const float* att_d1 = (const float*)d_in[6];
    const float* We1    = (const float*)d_in[7];
    const float* att_e1 = (const float*)d_in[8];
    const float* bias1  = (const float*)d_in[9];
    const float* prelu1 = (const float*)d_in[10];
    const float* W2     = (const float*)d_in[11];
    const float* att_s2 = (const float*)d_in[12];
    const float* att_d2 = (const float*)d_in[13];
    const float* We2    = (const float*)d_in[14];
    const float* att_e2 = (const float*)d_in[15];
    const float* bias2  = (const float*)d_in[16];
    const float* prelu2 = (const float*)d_in[17];
    const float* gW1    = (const float*)d_in[18];
    const float* gb1    = (const float*)d_in[19];
    const float* ga1    = (const float*)d_in[20];
    const float* gW2    = (const float*)d_in[21];
    const float* gb2    = (const float*)d_in[22];
    const float* ga2    = (const float*)d_in[23];
    const float* gW3    = (const float*)d_in[24];
    const float* gb3    = (const float*)d_in[25];
    const int* srcA = eidx;
    const int* dstA = eidx + N_EDGES;

    // ---- workspace (unions; total ~90 MB)
    char* wp = (char*)d_ws;
    auto alloc = [&](size_t bytes) -> void* {
        void* p = (void*)wp; wp += (bytes + 255) & ~(size_t)255; return p;
    };
    int*   deg  = (int*)alloc(N_NODES * 4);
    int*   cur  = (int*)alloc(N_NODES * 4);
    int*   offs = (int*)alloc((N_NODES + 1) * 4);
    int*   csr  = (int*)alloc(EA_EDGES * 4);
    float* vsd1 = (float*)alloc(CLIPD * 8 * 4);
    float* we12 = (float*)alloc(CLIPD * 8 * 4);
    float* vsd2 = (float*)alloc(HIDD * 8 * 4);
    float* ae   = (float*)alloc((size_t)EA_EDGES * 8 * 4);
    float* asd1 = (float*)alloc((size_t)N_NODES * 8 * 4);
    float* asd2 = (float*)alloc((size_t)N_NODES * 8 * 4);
    float* gate = (float*)alloc(N_NODES * 4);
    // union 1 (32MB): agg1 [N,3072]bf16 / agg2 [N,4096]bf16 / g2 [N,1024]f32
    char*  aggU = (char*)alloc((size_t)N_NODES * 4096 * 2);
    u16*   agg1 = (u16*)aggU;
    u16*   agg2 = (u16*)aggU;
    float* g2   = (float*)aggU;
    // union 2 (8MB): h1 / g1 (h1 dead before g1 written)
    u16*   h1   = (u16*)alloc((size_t)N_NODES * HIDD * 2);
    u16*   g1   = h1;
    u16*   h2   = (u16*)alloc((size_t)N_NODES * C2D * 2);          // 24MB
    u16*   Btb  = (u16*)alloc((size_t)C2D * 4096 * 2);             // 24MB shared B^T buf

    hipMemsetAsync(deg, 0, N_NODES * 4, stream);
    hipMemsetAsync(cur, 0, N_NODES * 4, stream);

    // CSR by dst (includes self loops)
    k_deg<<<(N_EDGES + 255) / 256, 256, 0, stream>>>(dstA, deg);
    k_scan<<<1, 1024, 0, stream>>>(deg, offs);
    k_fill<<<(EA_EDGES + 255) / 256, 256, 0, stream>>>(dstA, offs, cur, csr);

    // weight-side reductions: vsd1=[W1.att_src1|W1.att_dst1], we12=[We1.att_e1|We2.att_e2], vsd2 likewise
    k_reduce_w<<<CLIPD, 256, 0, stream>>>(W1, att_s1, att_d1, vsd1, HIDD, 0);
    k_reduce_w<<<CLIPD, 256, 0, stream>>>(We1, att_e1, nullptr, we12, HIDD, 0);
    k_reduce_w<<<HIDD, 256, 0, stream>>>(W2, att_s2, att_d2, vsd2, C2D, 0);
    k_reduce_w<<<CLIPD, 256, 0, stream>>>(We2, att_e2, nullptr, we12, C2D, 4);

    // edge attention logits for both layers; self-loop rows = incident mean (linearity)
    k_gemv8<float><<<N_EDGES / 4, 256, 0, stream>>>(eattr, CLIPD, we12, ae, N_EDGES);
    k_selfloop<<<(N_NODES + 255) / 256, 256, 0, stream>>>(ae, csr, offs, deg);
    k_gemv8<float><<<N_NODES / 4, 256, 0, stream>>>(x, CLIPD, vsd1, asd1, N_NODES);

    // ---- layer 1: aggregate in input space, then one fused GEMM (head-mean=0.25, bias, prelu)
    k_attn_agg<float><<<N_NODES, 256, 0, stream>>>(x, CLIPD, asd1, ae, 0, offs, csr, srcA, agg1);
    k_transpose<<<dim3(HIDD / 64, C2D / 64), dim3(64, 4), 0, stream>>>(W1, Btb, C2D, HIDD);
    k_gemm<64><<<dim3(HIDD / 64, N_NODES / 128), 256, 0, stream>>>(
        agg1, Btb, h1, bias1, prelu1, 0.25f, HIDD, C2D, 0);

    // ---- layer 2
    k_gemv8<u16><<<N_NODES / 4, 256, 0, stream>>>(h1, HIDD, vsd2, asd2, N_NODES);
    k_attn_agg<u16><<<N_NODES, 256, 0, stream>>>(h1, HIDD, asd2, ae, 4, offs, csr, srcA, agg2);
    k_transpose<<<dim3(C2D / 64, 4096 / 64), dim3(64, 4), 0, stream>>>(W2, Btb, 4096, C2D);
    k_gemm<128><<<dim3(C2D / 128, N_NODES / 128), 256, 0, stream>>>(
        agg2, Btb, h2, bias2, prelu2, 0.25f, C2D, 4096, 0);

    // ---- gate MLP (g2 kept fp32 for the softmax path)
    k_transpose<<<dim3(HIDD / 64, C2D / 64), dim3(64, 4), 0, stream>>>(gW1, Btb, C2D, HIDD);
    k_gemm<64><<<dim3(HIDD / 64, N_NODES / 128), 256, 0, stream>>>(
        h2, Btb, g1, gb1, ga1, 1.0f, HIDD, C2D, 0);
    k_transpose<<<dim3(HIDD / 64, HIDD / 64), dim3(64, 4), 0, stream>>>(gW2, Btb, HIDD, HIDD);
    k_gemm<64><<<dim3(HIDD / 64, N_NODES / 128), 256, 0, stream>>>(
        g1, Btb, (void*)g2, gb2, ga2, 1.0f, HIDD, HIDD, 1);
    k_gate<<<N_NODES / 4, 256, 0, stream>>>(g2, gW3, gb3, gate);

    // ---- attentional pooling over sorted batch (fp32 output)
    k_pool<<<dim3(NBATCH, 3), 256, 0, stream>>>(gate, h2, batch, (float*)d_out);
}

// Round 2
// 556.980 us; speedup vs baseline: 1.2074x; 1.0334x over previous
//
#include <hip/hip_runtime.h>
#include <stdint.h>
#include <stddef.h>

// ---------------- problem constants ----------------
#define N_NODES  4096
#define N_EDGES  12288
#define EA_EDGES 16384      // N_EDGES + N_NODES self loops
#define NBATCH   64
#define CLIPD    768
#define HIDD     1024
#define C2D      3072
#define NEG_SLOPE 0.2f
#define MAXDEG   96         // in-degree ~Poisson(3); P(>96) ~ 0

typedef unsigned short u16;
typedef short bf16x8 __attribute__((ext_vector_type(8)));   // 8 bf16 = 4 VGPRs (guide §3)
typedef float f32x4  __attribute__((ext_vector_type(4)));

static __device__ __forceinline__ float b2f(u16 u) {
    union { float f; unsigned int i; } v; v.i = ((unsigned int)u) << 16; return v.f;
}
static __device__ __forceinline__ u16 f2b(float f) {
    union { float f; unsigned int i; } v; v.f = f;
    unsigned int r = (v.i + 0x7fffu + ((v.i >> 16) & 1u)) >> 16;   // RNE
    return (u16)r;
}
// dtype-polymorphic 4-element vector load (fp32 or bf16 source) -> 4 floats
static __device__ __forceinline__ void ld4(const float* p, float v[4]) {
    float4 t = *(const float4*)p;
    v[0] = t.x; v[1] = t.y; v[2] = t.z; v[3] = t.w;
}
static __device__ __forceinline__ void ld4(const u16* p, float v[4]) {
    ushort4 t = *(const ushort4*)p;
    v[0] = b2f(t.x); v[1] = b2f(t.y); v[2] = b2f(t.z); v[3] = b2f(t.w);
}

static __device__ __forceinline__ float wsum(float v) {
#pragma unroll
    for (int o = 32; o > 0; o >>= 1) v += __shfl_xor(v, o, 64);
    return v;
}
static __device__ __forceinline__ float wmax(float v) {
#pragma unroll
    for (int o = 32; o > 0; o >>= 1) v = fmaxf(v, __shfl_xor(v, o, 64));
    return v;
}
static __device__ __forceinline__ int lower_bound(const int* a, int n, int key) {
    int lo = 0, hi = n;
    while (lo < hi) { int m = (lo + hi) >> 1; if (a[m] < key) lo = m + 1; else hi = m; }
    return lo;
}

// async global->LDS, 16B per lane. LDS dst is wave-uniform base + lane*16 (m104/m108);
// our LDS offsets are exactly tid*16, satisfying that constraint.
#define GLD16(gp, lp)                                                            \
    __builtin_amdgcn_global_load_lds((const __attribute__((address_space(1))) void*)(gp), \
                                     (__attribute__((address_space(3))) void*)(lp), 16, 0, 0)

// ---------------- CSR build ----------------
__global__ void k_deg(const int* __restrict__ dst, int* __restrict__ deg) {
    int e = blockIdx.x * 256 + threadIdx.x;
    if (e < N_EDGES) atomicAdd(&deg[dst[e]], 1);
}

__global__ void k_scan(const int* __restrict__ deg, int* __restrict__ offs) {
    __shared__ int s[1024];
    int t = threadIdx.x;
    int v[4]; int sum = 0;
#pragma unroll
    for (int i = 0; i < 4; i++) { v[i] = deg[t * 4 + i] + 1; sum += v[i]; }
    s[t] = sum; __syncthreads();
    for (int st = 1; st < 1024; st <<= 1) {
        int x = 0;
        if (t >= st) x = s[t - st];
        __syncthreads();
        s[t] += x;
        __syncthreads();
    }
    int run = s[t] - sum;
#pragma unroll
    for (int i = 0; i < 4; i++) { offs[t * 4 + i] = run; run += v[i]; }
    if (t == 1023) offs[N_NODES] = run;
}

__global__ void k_fill(const int* __restrict__ dst, const int* __restrict__ offs,
                       int* __restrict__ cur, int* __restrict__ csr) {
    int id = blockIdx.x * 256 + threadIdx.x;
    if (id >= EA_EDGES) return;
    int d = (id < N_EDGES) ? dst[id] : (id - N_EDGES);
    int p = atomicAdd(&cur[d], 1);
    csr[offs[d] + p] = id;
}

// ---------------- weight-side attention reductions (fp32 in, fp32 out) ----------------
// float4 over c (G13). R2: single fused dispatch for all four reductions (launch-gap cut).
static __device__ void reduce_w_body(const float* __restrict__ W, const float* __restrict__ attA,
                                     const float* __restrict__ attB, float* __restrict__ out,
                                     int C, int col0, int d) {
    int t = threadIdx.x;
    float acc[8] = {0, 0, 0, 0, 0, 0, 0, 0};
    for (int c = t * 4; c < C; c += 1024) {
#pragma unroll
        for (int h = 0; h < 4; h++) {
            float4 w = *(const float4*)&W[((size_t)d * 4 + h) * C + c];
            float4 a = *(const float4*)&attA[h * C + c];
            acc[h] += w.x * a.x + w.y * a.y + w.z * a.z + w.w * a.w;
            if (attB) {
                float4 bv = *(const float4*)&attB[h * C + c];
                acc[4 + h] += w.x * bv.x + w.y * bv.y + w.z * bv.z + w.w * bv.w;
            }
        }
    }
    __shared__ float red[4][8];
    int lane = t & 63, wv = t >> 6;
#pragma unroll
    for (int j = 0; j < 8; j++) acc[j] = wsum(acc[j]);
    if (lane == 0) {
#pragma unroll
        for (int j = 0; j < 8; j++) red[wv][j] = acc[j];
    }
    __syncthreads();
    if (t < 8) {
        float s = red[0][t] + red[1][t] + red[2][t] + red[3][t];
        if (attB) out[d * 8 + col0 + t] = s;
        else if (t < 4) out[d * 8 + col0 + t] = s;
    }
}

__global__ void k_reduce_all(const float* __restrict__ W1, const float* __restrict__ as1,
                             const float* __restrict__ ad1, float* __restrict__ vsd1,
                             const float* __restrict__ We1, const float* __restrict__ ae1,
                             const float* __restrict__ W2, const float* __restrict__ as2,
                             const float* __restrict__ ad2, float* __restrict__ vsd2,
                             const float* __restrict__ We2, const float* __restrict__ ae2,
                             float* __restrict__ we12) {
    int b = blockIdx.x;
    if (b < CLIPD)                   reduce_w_body(W1, as1, ad1, vsd1, HIDD, 0, b);
    else if (b < 2 * CLIPD)          reduce_w_body(We1, ae1, nullptr, we12, HIDD, 0, b - CLIPD);
    else if (b < 2 * CLIPD + HIDD)   reduce_w_body(W2, as2, ad2, vsd2, C2D, 0, b - 2 * CLIPD);
    else                             reduce_w_body(We2, ae2, nullptr, we12, C2D, 4, b - 2 * CLIPD - HIDD);
}

// skinny GEMV: out[row][0..7] = X[row,:] @ Wr[:,0..7]   (one wave per row, 4-wide k)
template <typename T>
static __device__ void gemv8_body(const T* __restrict__ X, int K, const float* __restrict__ Wr,
                                  float* __restrict__ out, int row) {
    int lane = threadIdx.x & 63;
    float acc[8] = {0, 0, 0, 0, 0, 0, 0, 0};
    const T* xp = X + (size_t)row * K;
    for (int k = lane * 4; k < K; k += 256) {
        float xv[4]; ld4(xp + k, xv);
#pragma unroll
        for (int kk = 0; kk < 4; kk++) {
            const float4* w = (const float4*)(Wr + (size_t)(k + kk) * 8);
            float4 w0 = w[0], w1 = w[1];
            acc[0] += xv[kk] * w0.x; acc[1] += xv[kk] * w0.y;
            acc[2] += xv[kk] * w0.z; acc[3] += xv[kk] * w0.w;
            acc[4] += xv[kk] * w1.x; acc[5] += xv[kk] * w1.y;
            acc[6] += xv[kk] * w1.z; acc[7] += xv[kk] * w1.w;
        }
    }
#pragma unroll
    for (int j = 0; j < 8; j++) acc[j] = wsum(acc[j]);
    if (lane == 0) {
#pragma unroll
        for (int j = 0; j < 8; j++) out[(size_t)row * 8 + j] = acc[j];
    }
}

template <typename T>
__global__ void k_gemv8(const T* __restrict__ X, int K, const float* __restrict__ Wr,
                        float* __restrict__ out, int rows) {
    int row = blockIdx.x * 4 + (threadIdx.x >> 6);
    if (row < rows) gemv8_body(X, K, Wr, out, row);
}

// R2: fused dual gemv (eattr->ae and x->asd1 are independent; one dispatch)
__global__ void k_gemv8_dual(const float* __restrict__ Xa, const float* __restrict__ Wa,
                             float* __restrict__ outA, int rowsA,
                             const float* __restrict__ Xb, const float* __restrict__ Wb,
                             float* __restrict__ outB) {
    int row = blockIdx.x * 4 + (threadIdx.x >> 6);
    if (row < rowsA) gemv8_body(Xa, CLIPD, Wa, outA, row);
    else             gemv8_body(Xb, CLIPD, Wb, outB, row - rowsA);
}

// self-loop edge attention = mean of incident real edges' a_e (linearity of mean_attr @ w)
__global__ void k_selfloop(float* __restrict__ ae, const int* __restrict__ csr,
                           const int* __restrict__ offs, const int* __restrict__ deg) {
    int n = blockIdx.x * 256 + threadIdx.x;
    if (n >= N_NODES) return;
    float s[8] = {0, 0, 0, 0, 0, 0, 0, 0};
    int lo = offs[n], hi = offs[n + 1];
    for (int i = lo; i < hi; i++) {
        int eid = csr[i];
        if (eid < N_EDGES) {
            const float4* p = (const float4*)(ae + (size_t)eid * 8);
            float4 a = p[0], b = p[1];
            s[0] += a.x; s[1] += a.y; s[2] += a.z; s[3] += a.w;
            s[4] += b.x; s[5] += b.y; s[6] += b.z; s[7] += b.w;
        }
    }
    float inv = 1.0f / (float)(deg[n] > 0 ? deg[n] : 1);
    float4* o = (float4*)(ae + (size_t)(N_EDGES + n) * 8);
    float4 o0, o1;
    o0.x = s[0] * inv; o0.y = s[1] * inv; o0.z = s[2] * inv; o0.w = s[3] * inv;
    o1.x = s[4] * inv; o1.y = s[5] * inv; o1.z = s[6] * inv; o1.w = s[7] * inv;
    o[0] = o0; o[1] = o1;
}

// per-dst-node attention softmax + aggregation in INPUT feature space:
// agg[n, d*4+h] = sum_e coef[e,h] * feat[src_e, d]  (bf16 out; column order = W's natural layout)
// wave-parallel softmax (one wave per head) + 4-features/thread vector path.
template <typename T>
__global__ void k_attn_agg(const T* __restrict__ feat, int D,
                           const float* __restrict__ asd, const float* __restrict__ ae, int aecol,
                           const int* __restrict__ offs, const int* __restrict__ csr,
                           const int* __restrict__ src, u16* __restrict__ agg) {
    int n = blockIdx.x, t = threadIdx.x;
    __shared__ int sl[MAXDEG];
    __shared__ float cf[MAXDEG][4];
    int lo = offs[n];
    int cnt = offs[n + 1] - lo;
    if (cnt > MAXDEG) cnt = MAXDEG;
    for (int i = t; i < cnt; i += 256) {
        int eid = csr[lo + i];
        int s = (eid < N_EDGES) ? src[eid] : n;
        sl[i] = s;
#pragma unroll
        for (int h = 0; h < 4; h++) {
            float al = asd[(size_t)s * 8 + h] + asd[(size_t)n * 8 + 4 + h] +
                       ae[(size_t)eid * 8 + aecol + h];
            cf[i][h] = (al >= 0.f) ? al : NEG_SLOPE * al;
        }
    }
    __syncthreads();
    {   // head = wave index: all 4 waves active, shuffle-reduce softmax
        int wv = t >> 6, lane = t & 63;
        float mx = -1e30f;
        for (int i = lane; i < cnt; i += 64) mx = fmaxf(mx, cf[i][wv]);
        mx = wmax(mx);
        float ds = 0.f;
        for (int i = lane; i < cnt; i += 64) {
            float e = __expf(cf[i][wv] - mx); cf[i][wv] = e; ds += e;
        }
        ds = wsum(ds);
        float inv = 1.0f / (ds + 1e-16f);
        for (int i = lane; i < cnt; i += 64) cf[i][wv] *= inv;
    }
    __syncthreads();
    for (int d4 = t * 4; d4 < D; d4 += 1024) {
        float a[4][4] = {};                     // [dj][head]
        for (int i = 0; i < cnt; i++) {
            float4 c4 = *(const float4*)cf[i];  // 4 heads, LDS broadcast
            float v[4]; ld4(feat + (size_t)sl[i] * D + d4, v);
#pragma unroll
            for (int dj = 0; dj < 4; dj++) {
                a[dj][0] += c4.x * v[dj]; a[dj][1] += c4.y * v[dj];
                a[dj][2] += c4.z * v[dj]; a[dj][3] += c4.w * v[dj];
            }
        }
        u16* op = agg + (size_t)n * 4 * D + (size_t)d4 * 4;
#pragma unroll
        for (int dj = 0; dj < 4; dj++) {
            ushort4 pk;
            pk.x = f2b(a[dj][0]); pk.y = f2b(a[dj][1]);
            pk.z = f2b(a[dj][2]); pk.w = f2b(a[dj][3]);
            *(ushort4*)(op + dj * 4) = pk;
        }
    }
}

// ---------------- transpose + downcast (fp32 [R,C] -> bf16 [C,R]) ----------------
// ushort4 stores; LDS read tile[s4+k][j]: bank = (4*(s4+k)+j)%32 covers all residues 2x = free.
__global__ void k_transpose(const float* __restrict__ in, u16* __restrict__ out, int R, int C) {
    __shared__ float tile[64][65];
    int tx = threadIdx.x, ty = threadIdx.y;
    int rb = blockIdx.y * 64, cb = blockIdx.x * 64;
    for (int i = ty; i < 64; i += 4) tile[i][tx] = in[(size_t)(rb + i) * C + cb + tx];
    __syncthreads();
    int linear = ty * 64 + tx;
#pragma unroll
    for (int jj = 0; jj < 4; jj++) {
        int idx = linear + jj * 256;
        int j = idx >> 4, s4 = (idx & 15) * 4;
        ushort4 pk;
        pk.x = f2b(tile[s4 + 0][j]);
        pk.y = f2b(tile[s4 + 1][j]);
        pk.z = f2b(tile[s4 + 2][j]);
        pk.w = f2b(tile[s4 + 3][j]);
        *(ushort4*)(out + (size_t)(cb + j) * R + rb + s4) = pk;
    }
}

// ---------------- MFMA GEMM: C = prelu(scale * A@Bt^T + bias) ----------------
// A [M,K] bf16 row-major, Bt [N,K] bf16 row-major. 128xBN tile, 4 waves.
// KSUB = 64-wide k-subtiles staged per barrier pair (R2): KSUB=2 doubles
// MFMA-per-barrier for the BN=64 GEMMs (the m97-structure stall is the
// vmcnt(0)+s_barrier drain). LDS at BN=64,KSUB=2 is 48KB -> still 3 blocks/CU
// by LDS (grid gives 2), so no m132-style occupancy cliff.
// Chunk mapping (per 64-wide subtile, unchanged): c -> row=c>>3, kb=(c&7)^(row&7).
// R2: bijective XCD-chunked block remap -- each XCD owns gx/8 consecutive
// n-columns (B-panels stay L2-resident; all XCDs walk A in lockstep). Every
// K-step drains vmcnt(0), so staging-load L2 misses sit on the critical path.
template <int BN, int KSUB>
__global__ __launch_bounds__(256, 2) void k_gemm(
        const u16* __restrict__ A, const u16* __restrict__ Bt, void* __restrict__ Cout,
        const float* __restrict__ bias, const float* __restrict__ prelu, float scale,
        int N, int K, int f32out) {
    constexpr int NJ = BN / 32;              // 16-wide n-subtiles per wave (2 waves along N)
    constexpr int NBCH = BN * 8 / 256;       // B chunks per thread per subtile (4 or 2)
    __shared__ __align__(16) u16 As[KSUB * 128 * 64];
    __shared__ __align__(16) u16 Bs[KSUB * BN * 64];
    int tid = threadIdx.x;
    int lane = tid & 63, wv = tid >> 6;
    int gx = gridDim.x;
    int bx = blockIdx.x, by = blockIdx.y;
    if ((gx & 7) == 0) {                     // bijective when gx%8==0 (all our grids)
        int flat = by * gx + bx;
        int nx_per = gx >> 3;
        int xcd = flat & 7, idx = flat >> 3;
        bx = xcd * nx_per + idx % nx_per;
        by = idx / nx_per;
    }
    int m0 = by * 128, n0 = bx * BN;
    const u16* agp[4]; int alo[4];
#pragma unroll
    for (int u = 0; u < 4; u++) {
        int c = tid + u * 256;
        int r = c >> 3, kb = (c & 7) ^ (r & 7);
        agp[u] = A + (size_t)(m0 + r) * K + kb * 8;
        alo[u] = c * 8;
    }
    const u16* bgp[NBCH]; int blo[NBCH];
#pragma unroll
    for (int u = 0; u < NBCH; u++) {
        int c = tid + u * 256;
        int r = c >> 3, kb = (c & 7) ^ (r & 7);
        bgp[u] = Bt + (size_t)(n0 + r) * K + kb * 8;
        blo[u] = c * 8;
    }
    int wm = wv & 1, wn = wv >> 1;
    int rl = lane & 15, q = lane >> 4;
    int swz = rl & 7;
    int mb = wm * 64 + rl;
    int nb = wn * (NJ * 16) + rl;
    f32x4 acc[4][NJ] = {};
    for (int k0 = 0; k0 < K; k0 += 64 * KSUB) {
        __syncthreads();                       // previous tile's LDS reads done
#pragma unroll
        for (int su = 0; su < KSUB; su++) {
#pragma unroll
            for (int u = 0; u < 4; u++)    GLD16(agp[u] + su * 64, As + su * (128 * 64) + alo[u]);
#pragma unroll
            for (int u = 0; u < NBCH; u++) GLD16(bgp[u] + su * 64, Bs + su * (BN * 64) + blo[u]);
        }
#pragma unroll
        for (int u = 0; u < 4; u++)    agp[u] += 64 * KSUB;
#pragma unroll
        for (int u = 0; u < NBCH; u++) bgp[u] += 64 * KSUB;
        __syncthreads();                       // drains vmcnt(0): staging landed
#pragma unroll
        for (int su = 0; su < KSUB; su++) {
            const u16* Asb = As + su * (128 * 64);
            const u16* Bsb = Bs + su * (BN * 64);
            bf16x8 af[4][2], bfr[NJ][2];
#pragma unroll
            for (int i = 0; i < 4; i++)
#pragma unroll
                for (int s = 0; s < 2; s++)
                    af[i][s] = *(const bf16x8*)(Asb + (((mb + i * 16) * 8 + ((q + 4 * s) ^ swz)) * 8));
#pragma unroll
            for (int j = 0; j < NJ; j++)
#pragma unroll
                for (int s = 0; s < 2; s++)
                    bfr[j][s] = *(const bf16x8*)(Bsb + (((nb + j * 16) * 8 + ((q + 4 * s) ^ swz)) * 8));
#pragma unroll
            for (int i = 0; i < 4; i++)
#pragma unroll
                for (int j = 0; j < NJ; j++) {
                    acc[i][j] = __builtin_amdgcn_mfma_f32_16x16x32_bf16(af[i][0], bfr[j][0], acc[i][j], 0, 0, 0);
                    acc[i][j] = __builtin_amdgcn_mfma_f32_16x16x32_bf16(af[i][1], bfr[j][1], acc[i][j], 0, 0, 0);
                }
        }
    }
    float pa = prelu[0];
    int r0w = (lane >> 4) * 4;
    int cc = lane & 15;
#pragma unroll
    for (int j = 0; j < NJ; j++) {
        int col = n0 + wn * (NJ * 16) + j * 16 + cc;
        float bv = bias[col];
#pragma unroll
        for (int i = 0; i < 4; i++) {
#pragma unroll
            for (int r = 0; r < 4; r++) {
                int row = m0 + wm * 64 + i * 16 + r0w + r;
                float v = acc[i][j][r] * scale + bv;
                v = (v >= 0.f) ? v : pa * v;
                if (f32out) ((float*)Cout)[(size_t)row * N + col] = v;
                else        ((u16*)Cout)[(size_t)row * N + col] = f2b(v);
            }
        }
    }
}

// ---------------- gate + pooling ----------------
__global__ void k_gate(const float* __restrict__ g2, const float* __restrict__ gW3,
                       const float* __restrict__ gb3, float* __restrict__ gate) {
    int wv = threadIdx.x >> 6, lane = threadIdx.x & 63;
    int n = blockIdx.x * 4 + wv;
    if (n >= N_NODES) return;
    float s = 0.f;
    const float* gp = g2 + (size_t)n * HIDD;
    for (int k = lane * 4; k < HIDD; k += 256) {
        float4 a = *(const float4*)(gp + k);
        float4 w = *(const float4*)(gW3 + k);
        s += a.x * w.x + a.y * w.y + a.z * w.z + a.w * w.w;
    }
    s = wsum(s);
    if (lane == 0) gate[n] = s + gb3[0];
}

// grid (64,3): C2D split across grid.y; ushort4 h2 loads, float4 stores.
__global__ void k_pool(const float* __restrict__ gate, const u16* __restrict__ h2,
                       const int* __restrict__ batch, float* __restrict__ out) {
    int b = blockIdx.x, t = threadIdx.x;
    int c = blockIdx.y * 1024 + t * 4;
    int lo = lower_bound(batch, N_NODES, b);
    int hi = lower_bound(batch, N_NODES, b + 1);
    int cnt = hi - lo;
    if (cnt <= 0) {
        float4 z; z.x = z.y = z.z = z.w = 0.f;
        *(float4*)(out + (size_t)b * C2D + c) = z;
        return;
    }
    if (cnt > 256) cnt = 256;   // multinomial(4096,1/64) max ~110; safety clamp
    __shared__ float w[256];
    __shared__ float red[4];
    int lane = t & 63, wv = t >> 6;
    float mx = -1e30f;
    for (int i = t; i < cnt; i += 256) mx = fmaxf(mx, gate[lo + i]);
    mx = wmax(mx);
    if (lane == 0) red[wv] = mx;
    __syncthreads();
    mx = fmaxf(fmaxf(red[0], red[1]), fmaxf(red[2], red[3]));
    __syncthreads();
    float ds = 0.f;
    for (int i = t; i < cnt; i += 256) { float e = __expf(gate[lo + i] - mx); w[i] = e; ds += e; }
    ds = wsum(ds);
    if (lane == 0) red[wv] = ds;
    __syncthreads();
    float inv = 1.0f / (red[0] + red[1] + red[2] + red[3] + 1e-16f);
    float4 acc; acc.x = acc.y = acc.z = acc.w = 0.f;
    const u16* hp = h2 + (size_t)lo * C2D + c;
    for (int i = 0; i < cnt; i++) {
        ushort4 hv = *(const ushort4*)hp; hp += C2D;
        float wi = w[i];
        acc.x += wi * b2f(hv.x); acc.y += wi * b2f(hv.y);
        acc.z += wi * b2f(hv.z); acc.w += wi * b2f(hv.w);
    }
    acc.x *= inv; acc.y *= inv; acc.z *= inv; acc.w *= inv;
    *(float4*)(out + (size_t)b * C2D + c) = acc;
}

// ---------------- launch ----------------
extern "C" void kernel_launch(void* const* d_in, const int* in_sizes, int n_in,
                              void* d_out, int out_size, void* d_ws, size_t ws_size,
                              hipStream_t stream) {
    (void)in_sizes; (void)n_in; (void)out_size; (void)ws_size;
    const float* x      = (const float*)d_in[0];
    const int*   eidx   = (const int*)d_in[1];
    const float* eattr  = (const float*)d_in[2];
    const int*   batch  = (const int*)d_in[3];
    const float* W1     = (const float*)d_in[4];
    const float* att_s1 = (const float*)d_in[5];
    const float* att_d1 = (const float*)d_in[6];
    const float* We1    = (const float*)d_in[7];
    const float* att_e1 = (const float*)d_in[8];
    const float* bias1  = (const float*)d_in[9];
    const float* prelu1 = (const float*)d_in[10];
    const float* W2     = (const float*)d_in[11];
    const float* att_s2 = (const float*)d_in[12];
    const float* att_d2 = (const float*)d_in[13];
    const float* We2    = (const float*)d_in[14];
    const float* att_e2 = (const float*)d_in[15];
    const float* bias2  = (const float*)d_in[16];
    const float* prelu2 = (const float*)d_in[17];
    const float* gW1    = (const float*)d_in[18];
    const float* gb1    = (const float*)d_in[19];
    const float* ga1    = (const float*)d_in[20];
    const float* gW2    = (const float*)d_in[21];
    const float* gb2    = (const float*)d_in[22];
    const float* ga2    = (const float*)d_in[23];
    const float* gW3    = (const float*)d_in[24];
    const float* gb3    = (const float*)d_in[25];
    const int* srcA = eidx;
    const int* dstA = eidx + N_EDGES;

    // ---- workspace (unions; total ~90 MB)
    char* wp = (char*)d_ws;
    auto alloc = [&](size_t bytes) -> void* {
        void* p = (void*)wp; wp += (bytes + 255) & ~(size_t)255; return p;
    };
    int*   deg  = (int*)alloc(N_NODES * 4);
    int*   cur  = (int*)alloc(N_NODES * 4);
    int*   offs = (int*)alloc((N_NODES + 1) * 4);
    int*   csr  = (int*)alloc(EA_EDGES * 4);
    float* vsd1 = (float*)alloc(CLIPD * 8 * 4);
    float* we12 = (float*)alloc(CLIPD * 8 * 4);
    float* vsd2 = (float*)alloc(HIDD * 8 * 4);
    float* ae   = (float*)alloc((size_t)EA_EDGES * 8 * 4);
    float* asd1 = (float*)alloc((size_t)N_NODES * 8 * 4);
    float* asd2 = (float*)alloc((size_t)N_NODES * 8 * 4);
    float* gate = (float*)alloc(N_NODES * 4);
    // union 1 (32MB): agg1 [N,3072]bf16 / agg2 [N,4096]bf16 / g2 [N,1024]f32
    char*  aggU = (char*)alloc((size_t)N_NODES * 4096 * 2);
    u16*   agg1 = (u16*)aggU;
    u16*   agg2 = (u16*)aggU;
    float* g2   = (float*)aggU;
    // union 2 (8MB): h1 / g1 (h1 dead before g1 written)
    u16*   h1   = (u16*)alloc((size_t)N_NODES * HIDD * 2);
    u16*   g1   = h1;
    u16*   h2   = (u16*)alloc((size_t)N_NODES * C2D * 2);          // 24MB
    u16*   Btb  = (u16*)alloc((size_t)C2D * 4096 * 2);             // 24MB shared B^T buf

    hipMemsetAsync(deg, 0, N_NODES * 4, stream);
    hipMemsetAsync(cur, 0, N_NODES * 4, stream);

    // CSR by dst (includes self loops)
    k_deg<<<(N_EDGES + 255) / 256, 256, 0, stream>>>(dstA, deg);
    k_scan<<<1, 1024, 0, stream>>>(deg, offs);
    k_fill<<<(EA_EDGES + 255) / 256, 256, 0, stream>>>(dstA, offs, cur, csr);

    // weight-side reductions, fused: vsd1=[W1.as|W1.ad], we12=[We1.ae1|We2.ae2], vsd2=[W2.as|W2.ad]
    k_reduce_all<<<2 * CLIPD + HIDD + CLIPD, 256, 0, stream>>>(
        W1, att_s1, att_d1, vsd1, We1, att_e1, W2, att_s2, att_d2, vsd2, We2, att_e2, we12);

    // edge attention logits (both layers) + node src/dst logits for layer 1, fused
    k_gemv8_dual<<<(N_EDGES + N_NODES) / 4, 256, 0, stream>>>(
        eattr, we12, ae, N_EDGES, x, vsd1, asd1);
    k_selfloop<<<(N_NODES + 255) / 256, 256, 0, stream>>>(ae, csr, offs, deg);

    // ---- layer 1: aggregate in input space, then one fused GEMM (head-mean=0.25, bias, prelu)
    k_attn_agg<float><<<N_NODES, 256, 0, stream>>>(x, CLIPD, asd1, ae, 0, offs, csr, srcA, agg1);
    k_transpose<<<dim3(HIDD / 64, C2D / 64), dim3(64, 4), 0, stream>>>(W1, Btb, C2D, HIDD);
    k_gemm<64, 2><<<dim3(HIDD / 64, N_NODES / 128), 256, 0, stream>>>(
        agg1, Btb, h1, bias1, prelu1, 0.25f, HIDD, C2D, 0);

    // ---- layer 2
    k_gemv8<u16><<<N_NODES / 4, 256, 0, stream>>>(h1, HIDD, vsd2, asd2, N_NODES);
    k_attn_agg<u16><<<N_NODES, 256, 0, stream>>>(h1, HIDD, asd2, ae, 4, offs, csr, srcA, agg2);
    k_transpose<<<dim3(C2D / 64, 4096 / 64), dim3(64, 4), 0, stream>>>(W2, Btb, 4096, C2D);
    k_gemm<128, 1><<<dim3(C2D / 128, N_NODES / 128), 256, 0, stream>>>(
        agg2, Btb, h2, bias2, prelu2, 0.25f, C2D, 4096, 0);

    // ---- gate MLP (g2 kept fp32 for the softmax path)
    k_transpose<<<dim3(HIDD / 64, C2D / 64), dim3(64, 4), 0, stream>>>(gW1, Btb, C2D, HIDD);
    k_gemm<64, 2><<<dim3(HIDD / 64, N_NODES / 128), 256, 0, stream>>>(
        h2, Btb, g1, gb1, ga1, 1.0f, HIDD, C2D, 0);
    k_transpose<<<dim3(HIDD / 64, HIDD / 64), dim3(64, 4), 0, stream>>>(gW2, Btb, HIDD, HIDD);
    k_gemm<64, 2><<<dim3(HIDD / 64, N_NODES / 128), 256, 0, stream>>>(
        g1, Btb, (void*)g2, gb2, ga2, 1.0f, HIDD, HIDD, 1);
    k_gate<<<N_NODES / 4, 256, 0, stream>>>(g2, gW3, gb3, gate);

    // ---- attentional pooling over sorted batch (fp32 output)
    k_pool<<<dim3(NBATCH, 3), 256, 0, stream>>>(gate, h2, batch, (float*)d_out);
}

// Round 3
// 555.250 us; speedup vs baseline: 1.2111x; 1.0031x over previous
//
#include <hip/hip_runtime.h>
#include <stdint.h>
#include <stddef.h>

// ---------------- problem constants ----------------
#define N_NODES  4096
#define N_EDGES  12288
#define EA_EDGES 16384      // N_EDGES + N_NODES self loops
#define NBATCH   64
#define CLIPD    768
#define HIDD     1024
#define C2D      3072
#define NEG_SLOPE 0.2f
#define MAXDEG   96         // in-degree ~Poisson(3); P(>96) ~ 0

typedef unsigned short u16;
typedef short bf16x8 __attribute__((ext_vector_type(8)));   // 8 bf16 = 4 VGPRs (guide §3)
typedef float f32x4  __attribute__((ext_vector_type(4)));

static __device__ __forceinline__ float b2f(u16 u) {
    union { float f; unsigned int i; } v; v.i = ((unsigned int)u) << 16; return v.f;
}
static __device__ __forceinline__ u16 f2b(float f) {
    union { float f; unsigned int i; } v; v.f = f;
    unsigned int r = (v.i + 0x7fffu + ((v.i >> 16) & 1u)) >> 16;   // RNE
    return (u16)r;
}
// dtype-polymorphic 4-element vector load (fp32 or bf16 source) -> 4 floats
static __device__ __forceinline__ void ld4(const float* p, float v[4]) {
    float4 t = *(const float4*)p;
    v[0] = t.x; v[1] = t.y; v[2] = t.z; v[3] = t.w;
}
static __device__ __forceinline__ void ld4(const u16* p, float v[4]) {
    ushort4 t = *(const ushort4*)p;
    v[0] = b2f(t.x); v[1] = b2f(t.y); v[2] = b2f(t.z); v[3] = b2f(t.w);
}

static __device__ __forceinline__ float wsum(float v) {
#pragma unroll
    for (int o = 32; o > 0; o >>= 1) v += __shfl_xor(v, o, 64);
    return v;
}
static __device__ __forceinline__ float wmax(float v) {
#pragma unroll
    for (int o = 32; o > 0; o >>= 1) v = fmaxf(v, __shfl_xor(v, o, 64));
    return v;
}
static __device__ __forceinline__ int lower_bound(const int* a, int n, int key) {
    int lo = 0, hi = n;
    while (lo < hi) { int m = (lo + hi) >> 1; if (a[m] < key) lo = m + 1; else hi = m; }
    return lo;
}

// async global->LDS, 16B per lane. LDS dst is wave-uniform base + lane*16 (m104/m108);
// our LDS offsets are exactly tid*16, satisfying that constraint.
#define GLD16(gp, lp)                                                            \
    __builtin_amdgcn_global_load_lds((const __attribute__((address_space(1))) void*)(gp), \
                                     (__attribute__((address_space(3))) void*)(lp), 16, 0, 0)

// ---------------- CSR build ----------------
__global__ void k_deg(const int* __restrict__ dst, int* __restrict__ deg) {
    int e = blockIdx.x * 256 + threadIdx.x;
    if (e < N_EDGES) atomicAdd(&deg[dst[e]], 1);
}

__global__ void k_scan(const int* __restrict__ deg, int* __restrict__ offs) {
    __shared__ int s[1024];
    int t = threadIdx.x;
    int v[4]; int sum = 0;
#pragma unroll
    for (int i = 0; i < 4; i++) { v[i] = deg[t * 4 + i] + 1; sum += v[i]; }
    s[t] = sum; __syncthreads();
    for (int st = 1; st < 1024; st <<= 1) {
        int x = 0;
        if (t >= st) x = s[t - st];
        __syncthreads();
        s[t] += x;
        __syncthreads();
    }
    int run = s[t] - sum;
#pragma unroll
    for (int i = 0; i < 4; i++) { offs[t * 4 + i] = run; run += v[i]; }
    if (t == 1023) offs[N_NODES] = run;
}

__global__ void k_fill(const int* __restrict__ dst, const int* __restrict__ offs,
                       int* __restrict__ cur, int* __restrict__ csr) {
    int id = blockIdx.x * 256 + threadIdx.x;
    if (id >= EA_EDGES) return;
    int d = (id < N_EDGES) ? dst[id] : (id - N_EDGES);
    int p = atomicAdd(&cur[d], 1);
    csr[offs[d] + p] = id;
}

// ---------------- weight-side attention reductions (fp32 in, fp32 out) ----------------
static __device__ void reduce_w_body(const float* __restrict__ W, const float* __restrict__ attA,
                                     const float* __restrict__ attB, float* __restrict__ out,
                                     int C, int col0, int d) {
    int t = threadIdx.x;
    float acc[8] = {0, 0, 0, 0, 0, 0, 0, 0};
    for (int c = t * 4; c < C; c += 1024) {
#pragma unroll
        for (int h = 0; h < 4; h++) {
            float4 w = *(const float4*)&W[((size_t)d * 4 + h) * C + c];
            float4 a = *(const float4*)&attA[h * C + c];
            acc[h] += w.x * a.x + w.y * a.y + w.z * a.z + w.w * a.w;
            if (attB) {
                float4 bv = *(const float4*)&attB[h * C + c];
                acc[4 + h] += w.x * bv.x + w.y * bv.y + w.z * bv.z + w.w * bv.w;
            }
        }
    }
    __shared__ float red[4][8];
    int lane = t & 63, wv = t >> 6;
#pragma unroll
    for (int j = 0; j < 8; j++) acc[j] = wsum(acc[j]);
    if (lane == 0) {
#pragma unroll
        for (int j = 0; j < 8; j++) red[wv][j] = acc[j];
    }
    __syncthreads();
    if (t < 8) {
        float s = red[0][t] + red[1][t] + red[2][t] + red[3][t];
        if (attB) out[d * 8 + col0 + t] = s;
        else if (t < 4) out[d * 8 + col0 + t] = s;
    }
}

__global__ void k_reduce_all(const float* __restrict__ W1, const float* __restrict__ as1,
                             const float* __restrict__ ad1, float* __restrict__ vsd1,
                             const float* __restrict__ We1, const float* __restrict__ ae1,
                             const float* __restrict__ W2, const float* __restrict__ as2,
                             const float* __restrict__ ad2, float* __restrict__ vsd2,
                             const float* __restrict__ We2, const float* __restrict__ ae2,
                             float* __restrict__ we12) {
    int b = blockIdx.x;
    if (b < CLIPD)                   reduce_w_body(W1, as1, ad1, vsd1, HIDD, 0, b);
    else if (b < 2 * CLIPD)          reduce_w_body(We1, ae1, nullptr, we12, HIDD, 0, b - CLIPD);
    else if (b < 2 * CLIPD + HIDD)   reduce_w_body(W2, as2, ad2, vsd2, C2D, 0, b - 2 * CLIPD);
    else                             reduce_w_body(We2, ae2, nullptr, we12, C2D, 4, b - 2 * CLIPD - HIDD);
}

// skinny GEMV: out[row][0..7] = X[row,:] @ Wr[:,0..7]   (one wave per row, 4-wide k)
template <typename T>
static __device__ void gemv8_body(const T* __restrict__ X, int K, const float* __restrict__ Wr,
                                  float* __restrict__ out, int row) {
    int lane = threadIdx.x & 63;
    float acc[8] = {0, 0, 0, 0, 0, 0, 0, 0};
    const T* xp = X + (size_t)row * K;
    for (int k = lane * 4; k < K; k += 256) {
        float xv[4]; ld4(xp + k, xv);
#pragma unroll
        for (int kk = 0; kk < 4; kk++) {
            const float4* w = (const float4*)(Wr + (size_t)(k + kk) * 8);
            float4 w0 = w[0], w1 = w[1];
            acc[0] += xv[kk] * w0.x; acc[1] += xv[kk] * w0.y;
            acc[2] += xv[kk] * w0.z; acc[3] += xv[kk] * w0.w;
            acc[4] += xv[kk] * w1.x; acc[5] += xv[kk] * w1.y;
            acc[6] += xv[kk] * w1.z; acc[7] += xv[kk] * w1.w;
        }
    }
#pragma unroll
    for (int j = 0; j < 8; j++) acc[j] = wsum(acc[j]);
    if (lane == 0) {
#pragma unroll
        for (int j = 0; j < 8; j++) out[(size_t)row * 8 + j] = acc[j];
    }
}

template <typename T>
__global__ void k_gemv8(const T* __restrict__ X, int K, const float* __restrict__ Wr,
                        float* __restrict__ out, int rows) {
    int row = blockIdx.x * 4 + (threadIdx.x >> 6);
    if (row < rows) gemv8_body(X, K, Wr, out, row);
}

// fused dual gemv (eattr->ae and x->asd1 are independent; one dispatch)
__global__ void k_gemv8_dual(const float* __restrict__ Xa, const float* __restrict__ Wa,
                             float* __restrict__ outA, int rowsA,
                             const float* __restrict__ Xb, const float* __restrict__ Wb,
                             float* __restrict__ outB) {
    int row = blockIdx.x * 4 + (threadIdx.x >> 6);
    if (row < rowsA) gemv8_body(Xa, CLIPD, Wa, outA, row);
    else             gemv8_body(Xb, CLIPD, Wb, outB, row - rowsA);
}

// per-dst-node attention softmax + aggregation in INPUT feature space:
// agg[n, d*4+h] = sum_e coef[e,h] * feat[src_e, d]
// R3: self-loop logit computed IN-KERNEL (mean of incident real edges' raw ae
// component, by linearity of mean_attr @ w_e) -- k_selfloop dispatch removed.
template <typename T>
__global__ void k_attn_agg(const T* __restrict__ feat, int D,
                           const float* __restrict__ asd, const float* __restrict__ ae, int aecol,
                           const int* __restrict__ offs, const int* __restrict__ csr,
                           const int* __restrict__ src, u16* __restrict__ agg) {
    int n = blockIdx.x, t = threadIdx.x;
    __shared__ int sl[MAXDEG];
    __shared__ float cf[MAXDEG][4];
    __shared__ float er[MAXDEG][4];   // raw edge-attn component (0 for self-loop slot)
    __shared__ int sidx;
    if (t == 0) sidx = -1;
    int lo = offs[n];
    int cnt = offs[n + 1] - lo;
    if (cnt > MAXDEG) cnt = MAXDEG;
    __syncthreads();
    for (int i = t; i < cnt; i += 256) {
        int eid = csr[lo + i];
        bool slf = (eid >= N_EDGES);
        int s = slf ? n : src[eid];
        sl[i] = s;
        if (slf) sidx = i;
#pragma unroll
        for (int h = 0; h < 4; h++) {
            float aev = slf ? 0.f : ae[(size_t)eid * 8 + aecol + h];
            er[i][h] = aev;
            float al = asd[(size_t)s * 8 + h] + asd[(size_t)n * 8 + 4 + h] + aev;
            cf[i][h] = (al >= 0.f) ? al : NEG_SLOPE * al;
        }
    }
    __syncthreads();
    int wv = t >> 6, lane = t & 63;
    {   // self-loop logit: head wv, wave-parallel mean of real-edge ae
        float se = 0.f;
        for (int i = lane; i < cnt; i += 64) se += er[i][wv];
        se = wsum(se);
        if (lane == 0 && sidx >= 0) {
            float al = asd[(size_t)n * 8 + wv] + asd[(size_t)n * 8 + 4 + wv] +
                       se / (float)(cnt > 1 ? cnt - 1 : 1);
            cf[sidx][wv] = (al >= 0.f) ? al : NEG_SLOPE * al;
        }
    }
    __syncthreads();
    {   // head = wave index: all 4 waves active, shuffle-reduce softmax
        float mx = -1e30f;
        for (int i = lane; i < cnt; i += 64) mx = fmaxf(mx, cf[i][wv]);
        mx = wmax(mx);
        float ds = 0.f;
        for (int i = lane; i < cnt; i += 64) {
            float e = __expf(cf[i][wv] - mx); cf[i][wv] = e; ds += e;
        }
        ds = wsum(ds);
        float inv = 1.0f / (ds + 1e-16f);
        for (int i = lane; i < cnt; i += 64) cf[i][wv] *= inv;
    }
    __syncthreads();
    for (int d4 = t * 4; d4 < D; d4 += 1024) {
        float a[4][4] = {};                     // [dj][head]
        for (int i = 0; i < cnt; i++) {
            float4 c4 = *(const float4*)cf[i];  // 4 heads, LDS broadcast
            float v[4]; ld4(feat + (size_t)sl[i] * D + d4, v);
#pragma unroll
            for (int dj = 0; dj < 4; dj++) {
                a[dj][0] += c4.x * v[dj]; a[dj][1] += c4.y * v[dj];
                a[dj][2] += c4.z * v[dj]; a[dj][3] += c4.w * v[dj];
            }
        }
        u16* op = agg + (size_t)n * 4 * D + (size_t)d4 * 4;
#pragma unroll
        for (int dj = 0; dj < 4; dj++) {
            ushort4 pk;
            pk.x = f2b(a[dj][0]); pk.y = f2b(a[dj][1]);
            pk.z = f2b(a[dj][2]); pk.w = f2b(a[dj][3]);
            *(ushort4*)(op + dj * 4) = pk;
        }
    }
}

// ---------------- transpose + downcast (fp32 [R,C] -> bf16 [C,R]) ----------------
// ushort4 stores; LDS read tile[s4+k][j]: bank = (4*(s4+k)+j)%32 covers all residues 2x = free.
static __device__ void transpose_body(const float* __restrict__ in, u16* __restrict__ out,
                                      int R, int C, int bx, int by) {
    __shared__ float tile[64][65];
    int tx = threadIdx.x, ty = threadIdx.y;
    int rb = by * 64, cb = bx * 64;
    for (int i = ty; i < 64; i += 4) tile[i][tx] = in[(size_t)(rb + i) * C + cb + tx];
    __syncthreads();
    int linear = ty * 64 + tx;
#pragma unroll
    for (int jj = 0; jj < 4; jj++) {
        int idx = linear + jj * 256;
        int j = idx >> 4, s4 = (idx & 15) * 4;
        ushort4 pk;
        pk.x = f2b(tile[s4 + 0][j]);
        pk.y = f2b(tile[s4 + 1][j]);
        pk.z = f2b(tile[s4 + 2][j]);
        pk.w = f2b(tile[s4 + 3][j]);
        *(ushort4*)(out + (size_t)(cb + j) * R + rb + s4) = pk;
    }
}

__global__ void k_transpose(const float* __restrict__ in, u16* __restrict__ out, int R, int C) {
    transpose_body(in, out, R, C, blockIdx.x, blockIdx.y);
}

// R3: all four weight transposes in ONE dispatch (removes 3 launch gaps; full-BW pass).
// tiles: W1 [3072,1024]=768, W2 [4096,3072]=3072, gW1 [3072,1024]=768, gW2 [1024,1024]=256.
__global__ void k_transpose_all(const float* __restrict__ W1, u16* __restrict__ W1t,
                                const float* __restrict__ W2, u16* __restrict__ W2t,
                                const float* __restrict__ gW1, u16* __restrict__ gW1t,
                                const float* __restrict__ gW2, u16* __restrict__ gW2t) {
    int b = blockIdx.x;
    const float* in; u16* out; int R, C, lb, txc;
    if (b < 768)       { in = W1;  out = W1t;  R = 3072; C = 1024; lb = b;        txc = 16; }
    else if (b < 3840) { in = W2;  out = W2t;  R = 4096; C = 3072; lb = b - 768;  txc = 48; }
    else if (b < 4608) { in = gW1; out = gW1t; R = 3072; C = 1024; lb = b - 3840; txc = 16; }
    else               { in = gW2; out = gW2t; R = 1024; C = 1024; lb = b - 4608; txc = 16; }
    transpose_body(in, out, R, C, lb % txc, lb / txc);
}

// ---------------- MFMA GEMM: C = prelu(scale * A@Bt^T + bias) ----------------
// A [M,K] bf16 row-major, Bt [N,K] bf16 row-major. 128xBN tile, 4 waves, KSUB
// 64-wide k-subtiles per barrier pair (doubles MFMA-per-barrier for BN=64).
// GATE mode (R3): instead of writing C, dot-reduce the block's 64-col slice of
// prelu(C) against gW3 (16-lane shuffle reduce) and atomicAdd into gate[row] --
// removes the g2 round-trip (33.6 MB) and the k_gate dispatch. gb3 is dropped:
// batch softmax is shift-invariant.
template <int BN, int KSUB, int GATE>
__global__ __launch_bounds__(256, 2) void k_gemm(
        const u16* __restrict__ A, const u16* __restrict__ Bt, void* __restrict__ Cout,
        const float* __restrict__ bias, const float* __restrict__ prelu, float scale,
        int N, int K, int f32out,
        const float* __restrict__ gW3, float* __restrict__ gateOut) {
    constexpr int NJ = BN / 32;              // 16-wide n-subtiles per wave (2 waves along N)
    constexpr int NBCH = BN * 8 / 256;       // B chunks per thread per subtile (4 or 2)
    __shared__ __align__(16) u16 As[KSUB * 128 * 64];
    __shared__ __align__(16) u16 Bs[KSUB * BN * 64];
    int tid = threadIdx.x;
    int lane = tid & 63, wv = tid >> 6;
    int gx = gridDim.x;
    int bx = blockIdx.x, by = blockIdx.y;
    if ((gx & 7) == 0) {                     // bijective when gx%8==0 (all our grids)
        int flat = by * gx + bx;
        int nx_per = gx >> 3;
        int xcd = flat & 7, idx = flat >> 3;
        bx = xcd * nx_per + idx % nx_per;
        by = idx / nx_per;
    }
    int m0 = by * 128, n0 = bx * BN;
    const u16* agp[4]; int alo[4];
#pragma unroll
    for (int u = 0; u < 4; u++) {
        int c = tid + u * 256;
        int r = c >> 3, kb = (c & 7) ^ (r & 7);
        agp[u] = A + (size_t)(m0 + r) * K + kb * 8;
        alo[u] = c * 8;
    }
    const u16* bgp[NBCH]; int blo[NBCH];
#pragma unroll
    for (int u = 0; u < NBCH; u++) {
        int c = tid + u * 256;
        int r = c >> 3, kb = (c & 7) ^ (r & 7);
        bgp[u] = Bt + (size_t)(n0 + r) * K + kb * 8;
        blo[u] = c * 8;
    }
    int wm = wv & 1, wn = wv >> 1;
    int rl = lane & 15, q = lane >> 4;
    int swz = rl & 7;
    int mb = wm * 64 + rl;
    int nb = wn * (NJ * 16) + rl;
    f32x4 acc[4][NJ] = {};
    for (int k0 = 0; k0 < K; k0 += 64 * KSUB) {
        __syncthreads();                       // previous tile's LDS reads done
#pragma unroll
        for (int su = 0; su < KSUB; su++) {
#pragma unroll
            for (int u = 0; u < 4; u++)    GLD16(agp[u] + su * 64, As + su * (128 * 64) + alo[u]);
#pragma unroll
            for (int u = 0; u < NBCH; u++) GLD16(bgp[u] + su * 64, Bs + su * (BN * 64) + blo[u]);
        }
#pragma unroll
        for (int u = 0; u < 4; u++)    agp[u] += 64 * KSUB;
#pragma unroll
        for (int u = 0; u < NBCH; u++) bgp[u] += 64 * KSUB;
        __syncthreads();                       // drains vmcnt(0): staging landed
#pragma unroll
        for (int su = 0; su < KSUB; su++) {
            const u16* Asb = As + su * (128 * 64);
            const u16* Bsb = Bs + su * (BN * 64);
            bf16x8 af[4][2], bfr[NJ][2];
#pragma unroll
            for (int i = 0; i < 4; i++)
#pragma unroll
                for (int s = 0; s < 2; s++)
                    af[i][s] = *(const bf16x8*)(Asb + (((mb + i * 16) * 8 + ((q + 4 * s) ^ swz)) * 8));
#pragma unroll
            for (int j = 0; j < NJ; j++)
#pragma unroll
                for (int s = 0; s < 2; s++)
                    bfr[j][s] = *(const bf16x8*)(Bsb + (((nb + j * 16) * 8 + ((q + 4 * s) ^ swz)) * 8));
#pragma unroll
            for (int i = 0; i < 4; i++)
#pragma unroll
                for (int j = 0; j < NJ; j++) {
                    acc[i][j] = __builtin_amdgcn_mfma_f32_16x16x32_bf16(af[i][0], bfr[j][0], acc[i][j], 0, 0, 0);
                    acc[i][j] = __builtin_amdgcn_mfma_f32_16x16x32_bf16(af[i][1], bfr[j][1], acc[i][j], 0, 0, 0);
                }
        }
    }
    float pa = prelu[0];
    int r0w = (lane >> 4) * 4;
    int cc = lane & 15;
    if (GATE) {
        float w3[NJ], bvj[NJ];
#pragma unroll
        for (int j = 0; j < NJ; j++) {
            int col = n0 + wn * (NJ * 16) + j * 16 + cc;
            w3[j] = gW3[col];
            bvj[j] = bias[col];
        }
#pragma unroll
        for (int i = 0; i < 4; i++) {
#pragma unroll
            for (int r = 0; r < 4; r++) {
                float p = 0.f;
#pragma unroll
                for (int j = 0; j < NJ; j++) {
                    float v = acc[i][j][r] * scale + bvj[j];
                    v = (v >= 0.f) ? v : pa * v;
                    p += v * w3[j];
                }
                // reduce across the 16 cc-lanes (masks < 16 stay within the q-group)
                p += __shfl_xor(p, 1, 64); p += __shfl_xor(p, 2, 64);
                p += __shfl_xor(p, 4, 64); p += __shfl_xor(p, 8, 64);
                if (cc == 0) {
                    int row = m0 + wm * 64 + i * 16 + r0w + r;
                    atomicAdd(&gateOut[row], p);
                }
            }
        }
        return;
    }
#pragma unroll
    for (int j = 0; j < NJ; j++) {
        int col = n0 + wn * (NJ * 16) + j * 16 + cc;
        float bv = bias[col];
#pragma unroll
        for (int i = 0; i < 4; i++) {
#pragma unroll
            for (int r = 0; r < 4; r++) {
                int row = m0 + wm * 64 + i * 16 + r0w + r;
                float v = acc[i][j][r] * scale + bv;
                v = (v >= 0.f) ? v : pa * v;
                if (f32out) ((float*)Cout)[(size_t)row * N + col] = v;
                else        ((u16*)Cout)[(size_t)row * N + col] = f2b(v);
            }
        }
    }
}

// ---------------- pooling ----------------
// grid (64,3): C2D split across grid.y; ushort4 h2 loads, float4 stores.
// gate[] contains sum over cols of prelu(g2)@gW3 (gb3 omitted: softmax shift-invariant).
__global__ void k_pool(const float* __restrict__ gate, const u16* __restrict__ h2,
                       const int* __restrict__ batch, float* __restrict__ out) {
    int b = blockIdx.x, t = threadIdx.x;
    int c = blockIdx.y * 1024 + t * 4;
    int lo = lower_bound(batch, N_NODES, b);
    int hi = lower_bound(batch, N_NODES, b + 1);
    int cnt = hi - lo;
    if (cnt <= 0) {
        float4 z; z.x = z.y = z.z = z.w = 0.f;
        *(float4*)(out + (size_t)b * C2D + c) = z;
        return;
    }
    if (cnt > 256) cnt = 256;   // multinomial(4096,1/64) max ~110; safety clamp
    __shared__ float w[256];
    __shared__ float red[4];
    int lane = t & 63, wv = t >> 6;
    float mx = -1e30f;
    for (int i = t; i < cnt; i += 256) mx = fmaxf(mx, gate[lo + i]);
    mx = wmax(mx);
    if (lane == 0) red[wv] = mx;
    __syncthreads();
    mx = fmaxf(fmaxf(red[0], red[1]), fmaxf(red[2], red[3]));
    __syncthreads();
    float ds = 0.f;
    for (int i = t; i < cnt; i += 256) { float e = __expf(gate[lo + i] - mx); w[i] = e; ds += e; }
    ds = wsum(ds);
    if (lane == 0) red[wv] = ds;
    __syncthreads();
    float inv = 1.0f / (red[0] + red[1] + red[2] + red[3] + 1e-16f);
    float4 acc; acc.x = acc.y = acc.z = acc.w = 0.f;
    const u16* hp = h2 + (size_t)lo * C2D + c;
    for (int i = 0; i < cnt; i++) {
        ushort4 hv = *(const ushort4*)hp; hp += C2D;
        float wi = w[i];
        acc.x += wi * b2f(hv.x); acc.y += wi * b2f(hv.y);
        acc.z += wi * b2f(hv.z); acc.w += wi * b2f(hv.w);
    }
    acc.x *= inv; acc.y *= inv; acc.z *= inv; acc.w *= inv;
    *(float4*)(out + (size_t)b * C2D + c) = acc;
}

// ---------------- launch ----------------
extern "C" void kernel_launch(void* const* d_in, const int* in_sizes, int n_in,
                              void* d_out, int out_size, void* d_ws, size_t ws_size,
                              hipStream_t stream) {
    (void)in_sizes; (void)n_in; (void)out_size;
    const float* x      = (const float*)d_in[0];
    const int*   eidx   = (const int*)d_in[1];
    const float* eattr  = (const float*)d_in[2];
    const int*   batch  = (const int*)d_in[3];
    const float* W1     = (const float*)d_in[4];
    const float* att_s1 = (const float*)d_in[5];
    const float* att_d1 = (const float*)d_in[6];
    const float* We1    = (const float*)d_in[7];
    const float* att_e1 = (const float*)d_in[8];
    const float* bias1  = (const float*)d_in[9];
    const float* prelu1 = (const float*)d_in[10];
    const float* W2     = (const float*)d_in[11];
    const float* att_s2 = (const float*)d_in[12];
    const float* att_d2 = (const float*)d_in[13];
    const float* We2    = (const float*)d_in[14];
    const float* att_e2 = (const float*)d_in[15];
    const float* bias2  = (const float*)d_in[16];
    const float* prelu2 = (const float*)d_in[17];
    const float* gW1    = (const float*)d_in[18];
    const float* gb1    = (const float*)d_in[19];
    const float* ga1    = (const float*)d_in[20];
    const float* gW2    = (const float*)d_in[21];
    const float* gb2    = (const float*)d_in[22];
    const float* ga2    = (const float*)d_in[23];
    const float* gW3    = (const float*)d_in[24];
    const int* srcA = eidx;
    const int* dstA = eidx + N_EDGES;

    // ---- workspace
    char* wp = (char*)d_ws;
    auto alloc = [&](size_t bytes) -> void* {
        void* p = (void*)wp; wp += (bytes + 255) & ~(size_t)255; return p;
    };
    int*   deg  = (int*)alloc(N_NODES * 4);
    int*   cur  = (int*)alloc(N_NODES * 4);
    int*   offs = (int*)alloc((N_NODES + 1) * 4);
    int*   csr  = (int*)alloc(EA_EDGES * 4);
    float* vsd1 = (float*)alloc(CLIPD * 8 * 4);
    float* we12 = (float*)alloc(CLIPD * 8 * 4);
    float* vsd2 = (float*)alloc(HIDD * 8 * 4);
    float* ae   = (float*)alloc((size_t)N_EDGES * 8 * 4);   // real edges only (self-loop in-kernel)
    float* asd1 = (float*)alloc((size_t)N_NODES * 8 * 4);
    float* asd2 = (float*)alloc((size_t)N_NODES * 8 * 4);
    float* gate = (float*)alloc(N_NODES * 4);
    // union 1 (33.6MB): agg1 [N,3072]bf16 / agg2 [N,4096]bf16
    char*  aggU = (char*)alloc((size_t)N_NODES * 4096 * 2);
    u16*   agg1 = (u16*)aggU;
    u16*   agg2 = (u16*)aggU;
    // union 2 (8.4MB): h1 / g1 (h1 dead before g1 written)
    u16*   h1   = (u16*)alloc((size_t)N_NODES * HIDD * 2);
    u16*   g1   = h1;
    u16*   h2   = (u16*)alloc((size_t)N_NODES * C2D * 2);          // 25.2MB
    // transpose outputs: fused single-dispatch path needs all four live (~40MB);
    // fall back to a shared sequential buffer if workspace is tight.
    size_t used = (size_t)(wp - (char*)d_ws);
    bool fused_tr = (ws_size == 0) || (ws_size > used + (size_t)42 * 1024 * 1024);
    u16 *W1t, *W2t, *gW1t, *gW2t;
    if (fused_tr) {
        W1t  = (u16*)alloc((size_t)1024 * 3072 * 2);
        W2t  = (u16*)alloc((size_t)3072 * 4096 * 2);
        gW1t = (u16*)alloc((size_t)1024 * 3072 * 2);
        gW2t = (u16*)alloc((size_t)1024 * 1024 * 2);
    } else {
        u16* Btb = (u16*)alloc((size_t)C2D * 4096 * 2);
        W1t = W2t = gW1t = gW2t = Btb;
    }

    hipMemsetAsync(deg, 0, N_NODES * 4, stream);
    hipMemsetAsync(cur, 0, N_NODES * 4, stream);
    hipMemsetAsync(gate, 0, N_NODES * 4, stream);

    // CSR by dst (includes self loops)
    k_deg<<<(N_EDGES + 255) / 256, 256, 0, stream>>>(dstA, deg);
    k_scan<<<1, 1024, 0, stream>>>(deg, offs);
    k_fill<<<(EA_EDGES + 255) / 256, 256, 0, stream>>>(dstA, offs, cur, csr);

    // weight-side reductions + all four weight transposes (input-only deps, front-loaded)
    k_reduce_all<<<2 * CLIPD + HIDD + CLIPD, 256, 0, stream>>>(
        W1, att_s1, att_d1, vsd1, We1, att_e1, W2, att_s2, att_d2, vsd2, We2, att_e2, we12);
    if (fused_tr)
        k_transpose_all<<<4864, dim3(64, 4), 0, stream>>>(W1, W1t, W2, W2t, gW1, gW1t, gW2, gW2t);

    // edge attention logits (both layers) + node src/dst logits for layer 1, fused
    k_gemv8_dual<<<(N_EDGES + N_NODES) / 4, 256, 0, stream>>>(
        eattr, we12, ae, N_EDGES, x, vsd1, asd1);

    // ---- layer 1: aggregate in input space, then one fused GEMM (head-mean=0.25, bias, prelu)
    k_attn_agg<float><<<N_NODES, 256, 0, stream>>>(x, CLIPD, asd1, ae, 0, offs, csr, srcA, agg1);
    if (!fused_tr)
        k_transpose<<<dim3(HIDD / 64, C2D / 64), dim3(64, 4), 0, stream>>>(W1, W1t, C2D, HIDD);
    k_gemm<64, 2, 0><<<dim3(HIDD / 64, N_NODES / 128), 256, 0, stream>>>(
        agg1, W1t, h1, bias1, prelu1, 0.25f, HIDD, C2D, 0, nullptr, nullptr);

    // ---- layer 2
    k_gemv8<u16><<<N_NODES / 4, 256, 0, stream>>>(h1, HIDD, vsd2, asd2, N_NODES);
    k_attn_agg<u16><<<N_NODES, 256, 0, stream>>>(h1, HIDD, asd2, ae, 4, offs, csr, srcA, agg2);
    if (!fused_tr)
        k_transpose<<<dim3(C2D / 64, 4096 / 64), dim3(64, 4), 0, stream>>>(W2, W2t, 4096, C2D);
    k_gemm<128, 1, 0><<<dim3(C2D / 128, N_NODES / 128), 256, 0, stream>>>(
        agg2, W2t, h2, bias2, prelu2, 0.25f, C2D, 4096, 0, nullptr, nullptr);

    // ---- gate MLP; final linear+gb3 folded into gate-2 GEMM epilogue (softmax shift-invariant)
    if (!fused_tr)
        k_transpose<<<dim3(HIDD / 64, C2D / 64), dim3(64, 4), 0, stream>>>(gW1, gW1t, C2D, HIDD);
    k_gemm<64, 2, 0><<<dim3(HIDD / 64, N_NODES / 128), 256, 0, stream>>>(
        h2, gW1t, g1, gb1, ga1, 1.0f, HIDD, C2D, 0, nullptr, nullptr);
    if (!fused_tr)
        k_transpose<<<dim3(HIDD / 64, HIDD / 64), dim3(64, 4), 0, stream>>>(gW2, gW2t, HIDD, HIDD);
    k_gemm<64, 2, 1><<<dim3(HIDD / 64, N_NODES / 128), 256, 0, stream>>>(
        g1, gW2t, nullptr, gb2, ga2, 1.0f, HIDD, HIDD, 0, gW3, gate);

    // ---- attentional pooling over sorted batch (fp32 output)
    k_pool<<<dim3(NBATCH, 3), 256, 0, stream>>>(gate, h2, batch, (float*)d_out);
}